// Round 12
// baseline (92.993 us; speedup 1.0000x reference)
//
#include <hip/hip_runtime.h>
#include <hip/hip_bf16.h>

#define NEL 16384

// ---- workspace layout (offsets in SHORTS from d_ws base) ----
#define W1B_OFF 0                         // bf16 W1 [128][64]
#define W2B_OFF 8192                      // bf16 W2 [128][128]
#define W3B_OFF 24576                     // bf16 W3 [512][128]
#define WS_WEIGHTS 90112
#define S1_OFF  90112                     // bf16 [NEL][128]
#define S2_OFF  (S1_OFF + NEL*128)
#define V_OFF   (S2_OFF + NEL*128)        // bf16 [NEL][512]
#define DZ2_OFF (V_OFF + NEL*512)         // bf16 [NEL*8][128]  (row m = e*8+j)

typedef __attribute__((ext_vector_type(8))) short bf16x8;
typedef __attribute__((ext_vector_type(4))) float f32x4;

__device__ __forceinline__ float bf2f(unsigned int u16) {
    unsigned int x = u16 << 16;
    float f; __builtin_memcpy(&f, &x, 4); return f;
}
__device__ __forceinline__ unsigned short f2bf(float f) {
    unsigned int x; __builtin_memcpy(&x, &f, 4);
    x = (x + 0x7FFFu + ((x >> 16) & 1u)) >> 16;
    return (unsigned short)x;
}
__device__ __forceinline__ void unpack8(uint4 q, float* f) {
    f[0] = bf2f(q.x & 0xFFFFu); f[1] = bf2f(q.x >> 16);
    f[2] = bf2f(q.y & 0xFFFFu); f[3] = bf2f(q.y >> 16);
    f[4] = bf2f(q.z & 0xFFFFu); f[5] = bf2f(q.z >> 16);
    f[6] = bf2f(q.w & 0xFFFFu); f[7] = bf2f(q.w >> 16);
}
__device__ __forceinline__ void sp_sig(float x, float& sp, float& sig) {
    float t = __expf(-fabsf(x));
    float r = __builtin_amdgcn_rcpf(1.f + t);
    sig = (x >= 0.f) ? r : 1.f - r;
    sp  = fmaxf(x, 0.f) + __logf(1.f + t);
}
__device__ __forceinline__ float tanh_fast(float x) {
    float t = __expf(-2.f * fabsf(x));
    float y = (1.f - t) * __builtin_amdgcn_rcpf(1.f + t);
    unsigned int xb, yb;
    __builtin_memcpy(&xb, &x, 4);
    __builtin_memcpy(&yb, &y, 4);
    yb |= (xb & 0x80000000u);
    float rr; __builtin_memcpy(&rr, &yb, 4);
    return rr;
}
__device__ __forceinline__ bf16x8 ldfrag(const unsigned short* p) {
    return *reinterpret_cast<const bf16x8*>(p);
}
__device__ __forceinline__ void cpu4(unsigned short* dst, const unsigned short* src) {
    *reinterpret_cast<uint4*>(dst) = *reinterpret_cast<const uint4*>(src);
}

// ---- prep: bf16 copies of W1, W2, W3 in [out][k] layout ----
__global__ void prep_weights(const float* __restrict__ W1,
                             const float* __restrict__ W2,
                             const float* __restrict__ W3,
                             unsigned short* __restrict__ wb) {
    int i = blockIdx.x * blockDim.x + threadIdx.x;
    if (i >= WS_WEIGHTS) return;
    float v;
    if (i < W2B_OFF) v = W1[i];
    else if (i < W3B_OFF) v = W2[i - W2B_OFF];
    else v = W3[i - W3B_OFF];
    wb[i] = f2bf(v);
}

// ============ K12: fwd1+fwd2+fwd3; weights direct from L2 (reuse=1 -> no staging) ============
// 16 elems/block, grid 1024. LDS only h/z1/z2 = 11008 B. 3 barriers total.
#define K12_LDS 11008
__global__ __launch_bounds__(256, 4)
void k12_fwd(const float* __restrict__ hg,
             const float* __restrict__ b1,
             const float* __restrict__ b2,
             const float* __restrict__ b3,
             const unsigned short* __restrict__ wsb,
             unsigned short* __restrict__ wso) {
    __shared__ __align__(16) char sm[K12_LDS];
    unsigned short* hs  = (unsigned short*)(sm);            // [16][72]
    unsigned short* z1s = (unsigned short*)(sm + 2304);     // [16][136]
    unsigned short* z2s = (unsigned short*)(sm + 6656);     // [16][136]
    unsigned short* S1g = wso + S1_OFF;
    unsigned short* S2g = wso + S2_OFF;
    unsigned short* Vg  = wso + V_OFF;

    const int tid = threadIdx.x;
    const int e0 = blockIdx.x * 16;
    const int lane = tid & 63;
    const int w = tid >> 6;            // wave 0..3
    const int r16 = lane & 15;
    const int kb = lane >> 4;
    const int crow = kb * 4;

    // load h (float4 -> bf16x4)
    {
        int row = tid >> 4, f4 = tid & 15;
        float4 hv = *reinterpret_cast<const float4*>(&hg[(e0 + row) * 64 + f4 * 4]);
        ushort2 lo = { f2bf(hv.x), f2bf(hv.y) };
        ushort2 hi = { f2bf(hv.z), f2bf(hv.w) };
        *reinterpret_cast<ushort2*>(&hs[row * 72 + f4 * 4]) = lo;
        *reinterpret_cast<ushort2*>(&hs[row * 72 + f4 * 4 + 2]) = hi;
    }
    __syncthreads();

    // fwd1: M=16 N=128 K=64; B direct from L2
    {
        const unsigned short* Ab = hs + r16 * 72 + kb * 8;
        bf16x8 a0 = ldfrag(Ab), a1 = ldfrag(Ab + 32);
        f32x4 acc[2] = {};
        #pragma unroll
        for (int t = 0; t < 2; ++t) {
            int col16 = (w * 2 + t) * 16 + r16;
            const unsigned short* Bb = wsb + W1B_OFF + col16 * 64 + kb * 8;
            acc[t] = __builtin_amdgcn_mfma_f32_16x16x32_bf16(a0, ldfrag(Bb), acc[t], 0, 0, 0);
            acc[t] = __builtin_amdgcn_mfma_f32_16x16x32_bf16(a1, ldfrag(Bb + 32), acc[t], 0, 0, 0);
        }
        #pragma unroll
        for (int t = 0; t < 2; ++t) {
            int col = (w * 2 + t) * 16 + r16;
            float bb = b1[col];
            #pragma unroll
            for (int rr = 0; rr < 4; ++rr) {
                int e = crow + rr;
                float sp, sg;
                sp_sig(acc[t][rr] + bb, sp, sg);
                z1s[e * 136 + col] = f2bf(sp);
                S1g[(e0 + e) * 128 + col] = f2bf(sg);
            }
        }
    }
    __syncthreads();

    // fwd2: M=16 N=128 K=128; B direct from L2; z2s separate (no overlay, no race)
    {
        const unsigned short* Ab = z1s + r16 * 136 + kb * 8;
        bf16x8 a[4];
        #pragma unroll
        for (int ks = 0; ks < 4; ++ks) a[ks] = ldfrag(Ab + ks * 32);
        f32x4 acc[2] = {};
        #pragma unroll
        for (int t = 0; t < 2; ++t) {
            int col16 = (w * 2 + t) * 16 + r16;
            const unsigned short* Bb = wsb + W2B_OFF + col16 * 128 + kb * 8;
            #pragma unroll
            for (int ks = 0; ks < 4; ++ks)
                acc[t] = __builtin_amdgcn_mfma_f32_16x16x32_bf16(a[ks], ldfrag(Bb + ks * 32), acc[t], 0, 0, 0);
        }
        #pragma unroll
        for (int t = 0; t < 2; ++t) {
            int col = (w * 2 + t) * 16 + r16;
            float bb = b2[col];
            #pragma unroll
            for (int rr = 0; rr < 4; ++rr) {
                int e = crow + rr;
                float sp, sg;
                sp_sig(acc[t][rr] + bb, sp, sg);
                z2s[e * 136 + col] = f2bf(sp);
                S2g[(e0 + e) * 128 + col] = f2bf(sg);
            }
        }
    }
    __syncthreads();

    // fwd3: A-frags hoisted once; 8 n-tiles x K=128 direct from L2; no barriers
    {
        const unsigned short* Ab = z2s + r16 * 136 + kb * 8;
        bf16x8 a[4];
        #pragma unroll
        for (int ks = 0; ks < 4; ++ks) a[ks] = ldfrag(Ab + ks * 32);
        #pragma unroll
        for (int nc = 0; nc < 4; ++nc) {
            #pragma unroll
            for (int t = 0; t < 2; ++t) {
                int c = nc * 128 + (w * 2 + t) * 16 + r16;
                const unsigned short* Bb = wsb + W3B_OFF + c * 128 + kb * 8;
                f32x4 acc = {};
                #pragma unroll
                for (int ks = 0; ks < 4; ++ks)
                    acc = __builtin_amdgcn_mfma_f32_16x16x32_bf16(a[ks], ldfrag(Bb + ks * 32), acc, 0, 0, 0);
                float bb = b3[c];
                #pragma unroll
                for (int rr = 0; rr < 4; ++rr) {
                    int e = crow + rr;
                    float v = tanh_fast(acc[rr] + bb);
                    Vg[(e0 + e) * 512 + c] = f2bf(v);
                }
            }
        }
    }
}

// ============ K3: T-build + jvp1 + jvp2 (dZ1 stays in LDS; W1/W2 staged: reuse=4) ============
// 8 elems/block, grid 2048, 3 blocks/CU (53376 B).
#define K3_LDS 53376
__global__ __launch_bounds__(256, 3)
void k3_jvp12(const float* __restrict__ sigg,
              unsigned short* __restrict__ wsb) {
    __shared__ __align__(16) char sm[K3_LDS];
    unsigned short* vs   = (unsigned short*)(sm);           // [8][520]
    unsigned short* w1s  = (unsigned short*)(sm + 8320);    // [128][72]
    unsigned short* ts   = (unsigned short*)(sm + 26752);   // [64][72]
    unsigned short* dz1s = (unsigned short*)(sm);           // [64][136] phase B
    unsigned short* w2s  = (unsigned short*)(sm + 17408);   // [128][136] phase B
    float* sigsm = (float*)(sm + 52224);                    // [288]
    const unsigned short* S1g = wsb + S1_OFF;
    const unsigned short* S2g = wsb + S2_OFF;
    const unsigned short* Vg  = wsb + V_OFF;
    unsigned short* DZ2g = wsb + DZ2_OFF;

    const int tid = threadIdx.x;
    const int e0 = blockIdx.x * 8;
    const int lane = tid & 63;
    const int w = tid >> 6;
    const int r16 = lane & 15;
    const int kb = lane >> 4;

    #pragma unroll
    for (int q = 0; q < 2; ++q) {
        int idx = q * 256 + tid;               // 0..511
        int row = idx >> 6, u4 = idx & 63;
        cpu4(&vs[row * 520 + u4 * 8], &Vg[(e0 + row) * 512 + u4 * 8]);
    }
    #pragma unroll
    for (int q = 0; q < 4; ++q) {
        int idx = q * 256 + tid;
        int row = idx >> 3, u4 = idx & 7;
        cpu4(&w1s[row * 72 + u4 * 8], &wsb[W1B_OFF + row * 64 + u4 * 8]);
    }
    #pragma unroll
    for (int q = 0; q < 2; ++q) {
        int idx = q * 256 + tid;
        if (idx < 288) sigsm[idx] = sigg[e0 * 36 + idx];
    }
    __syncthreads();

    // T-build: T[m=e*8+j][k] = sum_i c[i][j]_e * V[e][i*64+k]
    {
        int m = tid >> 2, kq = tid & 3;
        int e = m >> 3, j = m & 7;
        float c8[8];
        #pragma unroll
        for (int i = 0; i < 8; ++i) {
            float v = 0.f;
            if (i < j) {
                int p = 7 * i - i * (i - 1) / 2 + (j - i - 1);
                v = sigsm[e * 36 + 8 + p];
            } else if (i > j) {
                int p = 7 * j - j * (j - 1) / 2 + (i - j - 1);
                v = -sigsm[e * 36 + 8 + p];
            }
            c8[i] = v;
        }
        float acc[16] = {};
        #pragma unroll
        for (int i = 0; i < 8; ++i) {
            uint4 qa = *reinterpret_cast<const uint4*>(&vs[e * 520 + i * 64 + kq * 16]);
            uint4 qb = *reinterpret_cast<const uint4*>(&vs[e * 520 + i * 64 + kq * 16 + 8]);
            float fa[8], fb[8];
            unpack8(qa, fa); unpack8(qb, fb);
            #pragma unroll
            for (int kk = 0; kk < 8; ++kk) {
                acc[kk]     += c8[i] * fa[kk];
                acc[kk + 8] += c8[i] * fb[kk];
            }
        }
        unsigned short o[16];
        #pragma unroll
        for (int kk = 0; kk < 16; ++kk) o[kk] = f2bf(acc[kk]);
        uint4 qo;
        qo.x = (unsigned int)o[0] | ((unsigned int)o[1] << 16);
        qo.y = (unsigned int)o[2] | ((unsigned int)o[3] << 16);
        qo.z = (unsigned int)o[4] | ((unsigned int)o[5] << 16);
        qo.w = (unsigned int)o[6] | ((unsigned int)o[7] << 16);
        *reinterpret_cast<uint4*>(&ts[m * 72 + kq * 16]) = qo;
        qo.x = (unsigned int)o[8]  | ((unsigned int)o[9]  << 16);
        qo.y = (unsigned int)o[10] | ((unsigned int)o[11] << 16);
        qo.z = (unsigned int)o[12] | ((unsigned int)o[13] << 16);
        qo.w = (unsigned int)o[14] | ((unsigned int)o[15] << 16);
        *reinterpret_cast<uint4*>(&ts[m * 72 + kq * 16 + 8]) = qo;
    }
    __syncthreads();

    // jvp1: masked (T @ W1^T) held in registers   M=64 N=128 K=64
    float dz1v[8][4];
    const int rbase = w * 16 + kb * 4;
    const int e_loc = rbase >> 3;               // rbase&7 in {0,4} -> constant over rr
    {
        const unsigned short* Ab = ts + (w * 16 + r16) * 72 + kb * 8;
        bf16x8 a0 = ldfrag(Ab), a1 = ldfrag(Ab + 32);
        f32x4 acc[8] = {};
        #pragma unroll
        for (int nt = 0; nt < 8; ++nt) {
            const unsigned short* Bb = w1s + (nt * 16 + r16) * 72 + kb * 8;
            acc[nt] = __builtin_amdgcn_mfma_f32_16x16x32_bf16(a0, ldfrag(Bb), acc[nt], 0, 0, 0);
            acc[nt] = __builtin_amdgcn_mfma_f32_16x16x32_bf16(a1, ldfrag(Bb + 32), acc[nt], 0, 0, 0);
        }
        #pragma unroll
        for (int nt = 0; nt < 8; ++nt) {
            int col = nt * 16 + r16;
            float s1v = bf2f(S1g[(e0 + e_loc) * 128 + col]);
            #pragma unroll
            for (int rr = 0; rr < 4; ++rr)
                dz1v[nt][rr] = acc[nt][rr] * s1v;
        }
    }
    __syncthreads();   // all reads of ts/w1s/vs complete before overlay writes

    // write dz1s (overlay vs/w1s head) + stage w2s (overlay w1s tail/ts)
    #pragma unroll
    for (int nt = 0; nt < 8; ++nt) {
        int col = nt * 16 + r16;
        #pragma unroll
        for (int rr = 0; rr < 4; ++rr)
            dz1s[(rbase + rr) * 136 + col] = f2bf(dz1v[nt][rr]);
    }
    #pragma unroll
    for (int q = 0; q < 8; ++q) {
        int idx = q * 256 + tid;
        int row = idx >> 4, u4 = idx & 15;
        cpu4(&w2s[row * 136 + u4 * 8], &wsb[W2B_OFF + row * 128 + u4 * 8]);
    }
    __syncthreads();

    // jvp2: dZ2 = (dZ1 @ W2^T) .* s2 -> global   M=64 N=128 K=128
    {
        const unsigned short* Ab = dz1s + (w * 16 + r16) * 136 + kb * 8;
        bf16x8 a[4];
        #pragma unroll
        for (int ks = 0; ks < 4; ++ks) a[ks] = ldfrag(Ab + ks * 32);
        f32x4 acc[8] = {};
        #pragma unroll
        for (int nt = 0; nt < 8; ++nt) {
            const unsigned short* Bb = w2s + (nt * 16 + r16) * 136 + kb * 8;
            #pragma unroll
            for (int ks = 0; ks < 4; ++ks)
                acc[nt] = __builtin_amdgcn_mfma_f32_16x16x32_bf16(a[ks], ldfrag(Bb + ks * 32), acc[nt], 0, 0, 0);
        }
        #pragma unroll
        for (int nt = 0; nt < 8; ++nt) {
            int col = nt * 16 + r16;
            float s2v = bf2f(S2g[(e0 + e_loc) * 128 + col]);
            #pragma unroll
            for (int rr = 0; rr < 4; ++rr)
                DZ2g[(e0 * 8 + rbase + rr) * 128 + col] = f2bf(acc[nt][rr] * s2v);
        }
    }
}

// ============ K4: jvp3; A and W3 both direct from L2; LDS = sg1 only; 1 barrier ============
// 16 elems/block, grid 1024.
__global__ __launch_bounds__(256, 4)
void k4_jvp3(const float* __restrict__ sigg,
             const unsigned short* __restrict__ wsb,
             float* __restrict__ out) {
    __shared__ float sg1[16 * 9];                            // 576 B
    const unsigned short* Vg = wsb + V_OFF;
    const unsigned short* DZ2g = wsb + DZ2_OFF;

    const int tid = threadIdx.x;
    const int e0 = blockIdx.x * 16;
    const int lane = tid & 63;
    const int w = tid >> 6;            // wave w -> n-tile w (cols w*16..+15 of 64)
    const int r16 = lane & 15;
    const int kb = lane >> 4;
    const int crow = kb * 4;
    const int np = w * 16 + r16;

    if (tid < 128) {
        int e = tid >> 3, j7 = tid & 7;
        sg1[e * 9 + j7] = sigg[(e0 + e) * 36 + j7];
    }
    __syncthreads();

    float oacc[4] = {};
    const unsigned short* Agbase = DZ2g + (e0 + r16) * 8 * 128 + kb * 8;
    const unsigned short* Bgbase = wsb + W3B_OFF + np * 128 + kb * 8;

    #pragma unroll
    for (int j = 0; j < 8; ++j) {
        const unsigned short* Ag = Agbase + j * 128;
        bf16x8 a[4];
        #pragma unroll
        for (int ks = 0; ks < 4; ++ks) a[ks] = ldfrag(Ag + ks * 32);
        const unsigned short* Bg = Bgbase + j * 64 * 128;
        f32x4 acc = {};
        #pragma unroll
        for (int ks = 0; ks < 4; ++ks)
            acc = __builtin_amdgcn_mfma_f32_16x16x32_bf16(a[ks], ldfrag(Bg + ks * 32), acc, 0, 0, 0);

        #pragma unroll
        for (int rr = 0; rr < 4; ++rr) {
            int e = crow + rr;
            float v = bf2f(Vg[(e0 + e) * 512 + j * 64 + np]);
            float sv = sg1[e * 9 + j];
            oacc[rr] += sv * v + (1.f - v * v) * acc[rr];
        }
    }

    #pragma unroll
    for (int rr = 0; rr < 4; ++rr)
        out[(e0 + crow + rr) * 64 + np] = oacc[rr];
}

extern "C" void kernel_launch(void* const* d_in, const int* in_sizes, int n_in,
                              void* d_out, int out_size, void* d_ws, size_t ws_size,
                              hipStream_t stream) {
    const float* hg  = (const float*)d_in[0];
    const float* sg  = (const float*)d_in[1];
    const float* W1  = (const float*)d_in[2];
    const float* b1  = (const float*)d_in[3];
    const float* W2  = (const float*)d_in[4];
    const float* b2  = (const float*)d_in[5];
    const float* W3  = (const float*)d_in[6];
    const float* b3  = (const float*)d_in[7];
    float* outp = (float*)d_out;
    unsigned short* wsb = (unsigned short*)d_ws;

    hipLaunchKernelGGL(prep_weights, dim3((WS_WEIGHTS + 255) / 256), dim3(256), 0, stream,
                       W1, W2, W3, wsb);
    hipLaunchKernelGGL(k12_fwd, dim3(NEL / 16), dim3(256), 0, stream, hg, b1, b2, b3, wsb, wsb);
    hipLaunchKernelGGL(k3_jvp12, dim3(NEL / 8), dim3(256), 0, stream, sg, wsb);
    hipLaunchKernelGGL(k4_jvp3, dim3(NEL / 16), dim3(256), 0, stream, sg, wsb, outp);
}

// Round 13
// 84.663 us; speedup vs baseline: 1.0984x; 1.0984x over previous
//
#include <hip/hip_runtime.h>
#include <hip/hip_bf16.h>

#define NEL 16384

// ---- workspace layout (offsets in SHORTS from d_ws base) ----
#define W1B_OFF 0                         // bf16 W1 [128][64]
#define W2B_OFF 8192                      // bf16 W2 [128][128]
#define W3B_OFF 24576                     // bf16 W3 [512][128]
#define WS_WEIGHTS 90112
#define S1_OFF  90112                     // bf16 [NEL][128]
#define S2_OFF  (S1_OFF + NEL*128)
#define V_OFF   (S2_OFF + NEL*128)        // bf16 [NEL][512]

typedef __attribute__((ext_vector_type(8))) short bf16x8;
typedef __attribute__((ext_vector_type(4))) float f32x4;

__device__ __forceinline__ float bf2f(unsigned int u16) {
    unsigned int x = u16 << 16;
    float f; __builtin_memcpy(&f, &x, 4); return f;
}
__device__ __forceinline__ unsigned short f2bf(float f) {
    unsigned int x; __builtin_memcpy(&x, &f, 4);
    x = (x + 0x7FFFu + ((x >> 16) & 1u)) >> 16;
    return (unsigned short)x;
}
__device__ __forceinline__ void unpack8(uint4 q, float* f) {
    f[0] = bf2f(q.x & 0xFFFFu); f[1] = bf2f(q.x >> 16);
    f[2] = bf2f(q.y & 0xFFFFu); f[3] = bf2f(q.y >> 16);
    f[4] = bf2f(q.z & 0xFFFFu); f[5] = bf2f(q.z >> 16);
    f[6] = bf2f(q.w & 0xFFFFu); f[7] = bf2f(q.w >> 16);
}
__device__ __forceinline__ void sp_sig(float x, float& sp, float& sig) {
    float t = __expf(-fabsf(x));
    float r = __builtin_amdgcn_rcpf(1.f + t);
    sig = (x >= 0.f) ? r : 1.f - r;
    sp  = fmaxf(x, 0.f) + __logf(1.f + t);
}
__device__ __forceinline__ float tanh_fast(float x) {
    float t = __expf(-2.f * fabsf(x));
    float y = (1.f - t) * __builtin_amdgcn_rcpf(1.f + t);
    unsigned int xb, yb;
    __builtin_memcpy(&xb, &x, 4);
    __builtin_memcpy(&yb, &y, 4);
    yb |= (xb & 0x80000000u);
    float rr; __builtin_memcpy(&rr, &yb, 4);
    return rr;
}
__device__ __forceinline__ bf16x8 ldfrag(const unsigned short* p) {
    return *reinterpret_cast<const bf16x8*>(p);
}
__device__ __forceinline__ void cpu4(unsigned short* dst, const unsigned short* src) {
    *reinterpret_cast<uint4*>(dst) = *reinterpret_cast<const uint4*>(src);
}

// ---- prep: bf16 copies of W1, W2, W3 in [out][k] layout ----
__global__ void prep_weights(const float* __restrict__ W1,
                             const float* __restrict__ W2,
                             const float* __restrict__ W3,
                             unsigned short* __restrict__ wb) {
    int i = blockIdx.x * blockDim.x + threadIdx.x;
    if (i >= WS_WEIGHTS) return;
    float v;
    if (i < W2B_OFF) v = W1[i];
    else if (i < W3B_OFF) v = W2[i - W2B_OFF];
    else v = W3[i - W3B_OFF];
    wb[i] = f2bf(v);
}

// ============ K12: fwd1 + fwd2 + fwd3 (Z1, Z2 stay in LDS; staged weights) ============
// 16 elems/block, grid 1024, 4 blocks/CU. (R11 version — proven.)
#define K12_LDS 39168
__global__ __launch_bounds__(256, 4)
void k12_fwd(const float* __restrict__ hg,
             const float* __restrict__ b1,
             const float* __restrict__ b2,
             const float* __restrict__ b3,
             unsigned short* __restrict__ wsb) {
    __shared__ __align__(16) char sm[K12_LDS];
    unsigned short* w1s = (unsigned short*)(sm);            // [128][72]
    unsigned short* hs  = (unsigned short*)(sm + 18432);    // [16][72]
    unsigned short* w2s = (unsigned short*)(sm);            // [128][136] phase2
    unsigned short* wc  = (unsigned short*)(sm);            // [128][136] phase3
    unsigned short* z1s = (unsigned short*)(sm + 34816);    // [16][136]
    unsigned short* z2s = (unsigned short*)(sm + 34816);    // [16][136] overlays z1s
    unsigned short* S1g = wsb + S1_OFF;
    unsigned short* S2g = wsb + S2_OFF;
    unsigned short* Vg  = wsb + V_OFF;

    const int tid = threadIdx.x;
    const int e0 = blockIdx.x * 16;
    const int lane = tid & 63;
    const int w = tid >> 6;
    const int r16 = lane & 15;
    const int kb = lane >> 4;
    const int crow = kb * 4;

    #pragma unroll
    for (int q = 0; q < 4; ++q) {
        int idx = q * 256 + tid;
        int row = idx >> 3, u4 = idx & 7;
        cpu4(&w1s[row * 72 + u4 * 8], &wsb[W1B_OFF + row * 64 + u4 * 8]);
    }
    {
        int row = tid >> 4, f4 = tid & 15;
        float4 hv = *reinterpret_cast<const float4*>(&hg[(e0 + row) * 64 + f4 * 4]);
        ushort2 lo = { f2bf(hv.x), f2bf(hv.y) };
        ushort2 hi = { f2bf(hv.z), f2bf(hv.w) };
        *reinterpret_cast<ushort2*>(&hs[row * 72 + f4 * 4]) = lo;
        *reinterpret_cast<ushort2*>(&hs[row * 72 + f4 * 4 + 2]) = hi;
    }
    __syncthreads();

    // fwd1: M=16 N=128 K=64
    {
        const unsigned short* Ab = hs + r16 * 72 + kb * 8;
        bf16x8 a0 = ldfrag(Ab), a1 = ldfrag(Ab + 32);
        f32x4 acc[2] = {};
        #pragma unroll
        for (int t = 0; t < 2; ++t) {
            int col16 = (w * 2 + t) * 16 + r16;
            const unsigned short* Bb = w1s + col16 * 72 + kb * 8;
            acc[t] = __builtin_amdgcn_mfma_f32_16x16x32_bf16(a0, ldfrag(Bb), acc[t], 0, 0, 0);
            acc[t] = __builtin_amdgcn_mfma_f32_16x16x32_bf16(a1, ldfrag(Bb + 32), acc[t], 0, 0, 0);
        }
        #pragma unroll
        for (int t = 0; t < 2; ++t) {
            int col = (w * 2 + t) * 16 + r16;
            float bb = b1[col];
            #pragma unroll
            for (int rr = 0; rr < 4; ++rr) {
                int e = crow + rr;
                float sp, sg;
                sp_sig(acc[t][rr] + bb, sp, sg);
                z1s[e * 136 + col] = f2bf(sp);
                S1g[(e0 + e) * 128 + col] = f2bf(sg);
            }
        }
    }
    __syncthreads();

    #pragma unroll
    for (int q = 0; q < 8; ++q) {
        int idx = q * 256 + tid;
        int row = idx >> 4, u4 = idx & 15;
        cpu4(&w2s[row * 136 + u4 * 8], &wsb[W2B_OFF + row * 128 + u4 * 8]);
    }
    __syncthreads();

    // fwd2: race-protected overlay (A-frags held in regs behind barrier)
    {
        const unsigned short* Ab = z1s + r16 * 136 + kb * 8;
        bf16x8 a[4];
        #pragma unroll
        for (int ks = 0; ks < 4; ++ks) a[ks] = ldfrag(Ab + ks * 32);
        __syncthreads();
        f32x4 acc[2] = {};
        #pragma unroll
        for (int t = 0; t < 2; ++t) {
            int col16 = (w * 2 + t) * 16 + r16;
            const unsigned short* Bb = w2s + col16 * 136 + kb * 8;
            #pragma unroll
            for (int ks = 0; ks < 4; ++ks)
                acc[t] = __builtin_amdgcn_mfma_f32_16x16x32_bf16(a[ks], ldfrag(Bb + ks * 32), acc[t], 0, 0, 0);
        }
        #pragma unroll
        for (int t = 0; t < 2; ++t) {
            int col = (w * 2 + t) * 16 + r16;
            float bb = b2[col];
            #pragma unroll
            for (int rr = 0; rr < 4; ++rr) {
                int e = crow + rr;
                float sp, sg;
                sp_sig(acc[t][rr] + bb, sp, sg);
                z2s[e * 136 + col] = f2bf(sp);
                S2g[(e0 + e) * 128 + col] = f2bf(sg);
            }
        }
    }

    // fwd3: 4 chunks of 128 cols; wc overlays w2s
    for (int nc = 0; nc < 4; ++nc) {
        __syncthreads();
        #pragma unroll
        for (int q = 0; q < 8; ++q) {
            int idx = q * 256 + tid;
            int row = idx >> 4, u4 = idx & 15;
            cpu4(&wc[row * 136 + u4 * 8], &wsb[W3B_OFF + (nc * 128 + row) * 128 + u4 * 8]);
        }
        __syncthreads();

        const unsigned short* Ab = z2s + r16 * 136 + kb * 8;
        bf16x8 a[4];
        #pragma unroll
        for (int ks = 0; ks < 4; ++ks) a[ks] = ldfrag(Ab + ks * 32);
        f32x4 acc[2] = {};
        #pragma unroll
        for (int t = 0; t < 2; ++t) {
            int col16 = (w * 2 + t) * 16 + r16;
            const unsigned short* Bb = wc + col16 * 136 + kb * 8;
            #pragma unroll
            for (int ks = 0; ks < 4; ++ks)
                acc[t] = __builtin_amdgcn_mfma_f32_16x16x32_bf16(a[ks], ldfrag(Bb + ks * 32), acc[t], 0, 0, 0);
        }
        #pragma unroll
        for (int t = 0; t < 2; ++t) {
            int c = nc * 128 + (w * 2 + t) * 16 + r16;
            float bb = b3[c];
            #pragma unroll
            for (int rr = 0; rr < 4; ++rr) {
                int e = crow + rr;
                float v = tanh_fast(acc[t][rr] + bb);
                Vg[(e0 + e) * 512 + c] = f2bf(v);
            }
        }
    }
}

// ============ K3_ALL: T-build + jvp1 + jvp2 + jvp3 + output (j-major rows) ============
// 8 elems/block, grid 2048, 3 blocks/CU (54272 B).
// Phase A: vs[8][520]@0 | w1s[128][72]@8320 | ts[64][72]@26752 | sigs f32[288]@35968 | s1s@SLOT
// Phase B: dz1s[64][136]@0 | w2s[128][136]@17408 | s2s@SLOT
// Phase C: dz2s[64][136]@0 | w3j0@17408 | w3j1@34816 | sig1f then pj @SLOT
#define C3_SLOT 52224
#define C3_LDS  54272
__global__ __launch_bounds__(256, 3)
void k3_all(const float* __restrict__ sigg,
            const unsigned short* __restrict__ wsb,
            float* __restrict__ out) {
    __shared__ __align__(16) char sm[C3_LDS];
    unsigned short* vs    = (unsigned short*)(sm);           // [8][520]
    unsigned short* w1s   = (unsigned short*)(sm + 8320);    // [128][72]
    unsigned short* ts    = (unsigned short*)(sm + 26752);   // [64][72]
    float*          sigsm = (float*)(sm + 35968);            // [288] (phase A only)
    unsigned short* dz1s  = (unsigned short*)(sm);           // [64][136] phase B
    unsigned short* w2s   = (unsigned short*)(sm + 17408);   // [128][136] phase B
    unsigned short* dz2s  = (unsigned short*)(sm);           // [64][136] phase C
    unsigned short* w3j0  = (unsigned short*)(sm + 17408);   // [64][136] phase C
    unsigned short* w3j1  = (unsigned short*)(sm + 34816);   // [64][136] phase C
    unsigned short* s1s   = (unsigned short*)(sm + C3_SLOT); // [8][128] phase A
    unsigned short* s2s   = (unsigned short*)(sm + C3_SLOT); // [8][128] phase B
    float*          sig1f = (float*)(sm + C3_SLOT);          // [8][8] phase C (loop)
    float*          pjf   = (float*)(sm + C3_SLOT);          // [8][64] phase C (combine)

    const unsigned short* S1g = wsb + S1_OFF;
    const unsigned short* S2g = wsb + S2_OFF;
    const unsigned short* Vg  = wsb + V_OFF;

    const int tid = threadIdx.x;
    const int e0 = blockIdx.x * 8;
    const int lane = tid & 63;
    const int w = tid >> 6;
    const int r16 = lane & 15;
    const int kb = lane >> 4;
    const int crow = kb * 4;

    // ---- Phase A stage: V, W1, sigs, s1
    #pragma unroll
    for (int q = 0; q < 2; ++q) {
        int idx = q * 256 + tid;               // 0..511
        int row = idx >> 6, u4 = idx & 63;
        cpu4(&vs[row * 520 + u4 * 8], &Vg[(e0 + row) * 512 + u4 * 8]);
    }
    #pragma unroll
    for (int q = 0; q < 4; ++q) {
        int idx = q * 256 + tid;
        int row = idx >> 3, u4 = idx & 7;
        cpu4(&w1s[row * 72 + u4 * 8], &wsb[W1B_OFF + row * 64 + u4 * 8]);
    }
    #pragma unroll
    for (int q = 0; q < 2; ++q) {
        int idx = q * 256 + tid;
        if (idx < 288) sigsm[idx] = sigg[e0 * 36 + idx];
    }
    if (tid < 128) {
        int row = tid >> 4, u4 = tid & 15;
        cpu4(&s1s[row * 128 + u4 * 8], &S1g[(e0 + row) * 128 + u4 * 8]);
    }
    __syncthreads();

    // ---- T-build (J-MAJOR): T[m=j*8+e][k] = sum_i c[i][j]_e * V[e][i*64+k]
    {
        int m = tid >> 2, kq = tid & 3;
        int j = m >> 3, e = m & 7;
        float c8[8];
        #pragma unroll
        for (int i = 0; i < 8; ++i) {
            float v = 0.f;
            if (i < j) {
                int p = 7 * i - i * (i - 1) / 2 + (j - i - 1);
                v = sigsm[e * 36 + 8 + p];
            } else if (i > j) {
                int p = 7 * j - j * (j - 1) / 2 + (i - j - 1);
                v = -sigsm[e * 36 + 8 + p];
            }
            c8[i] = v;
        }
        float acc[16] = {};
        #pragma unroll
        for (int i = 0; i < 8; ++i) {
            uint4 qa = *reinterpret_cast<const uint4*>(&vs[e * 520 + i * 64 + kq * 16]);
            uint4 qb = *reinterpret_cast<const uint4*>(&vs[e * 520 + i * 64 + kq * 16 + 8]);
            float fa[8], fb[8];
            unpack8(qa, fa); unpack8(qb, fb);
            #pragma unroll
            for (int kk = 0; kk < 8; ++kk) {
                acc[kk]     += c8[i] * fa[kk];
                acc[kk + 8] += c8[i] * fb[kk];
            }
        }
        unsigned short o[16];
        #pragma unroll
        for (int kk = 0; kk < 16; ++kk) o[kk] = f2bf(acc[kk]);
        uint4 qo;
        qo.x = (unsigned int)o[0] | ((unsigned int)o[1] << 16);
        qo.y = (unsigned int)o[2] | ((unsigned int)o[3] << 16);
        qo.z = (unsigned int)o[4] | ((unsigned int)o[5] << 16);
        qo.w = (unsigned int)o[6] | ((unsigned int)o[7] << 16);
        *reinterpret_cast<uint4*>(&ts[m * 72 + kq * 16]) = qo;
        qo.x = (unsigned int)o[8]  | ((unsigned int)o[9]  << 16);
        qo.y = (unsigned int)o[10] | ((unsigned int)o[11] << 16);
        qo.z = (unsigned int)o[12] | ((unsigned int)o[13] << 16);
        qo.w = (unsigned int)o[14] | ((unsigned int)o[15] << 16);
        *reinterpret_cast<uint4*>(&ts[m * 72 + kq * 16 + 8]) = qo;
    }
    __syncthreads();

    const int rbase = w * 16 + crow;
    int e4[4];
    #pragma unroll
    for (int rr = 0; rr < 4; ++rr) e4[rr] = (crow + rr) & 7;  // e = m&7 (j-major)

    // ---- jvp1: (T @ W1^T) .* s1[e] -> registers   M=64 N=128 K=64
    float dz1v[8][4];
    {
        const unsigned short* Ab = ts + (w * 16 + r16) * 72 + kb * 8;
        bf16x8 a0 = ldfrag(Ab), a1 = ldfrag(Ab + 32);
        f32x4 acc[8] = {};
        #pragma unroll
        for (int nt = 0; nt < 8; ++nt) {
            const unsigned short* Bb = w1s + (nt * 16 + r16) * 72 + kb * 8;
            acc[nt] = __builtin_amdgcn_mfma_f32_16x16x32_bf16(a0, ldfrag(Bb), acc[nt], 0, 0, 0);
            acc[nt] = __builtin_amdgcn_mfma_f32_16x16x32_bf16(a1, ldfrag(Bb + 32), acc[nt], 0, 0, 0);
        }
        #pragma unroll
        for (int nt = 0; nt < 8; ++nt) {
            int col = nt * 16 + r16;
            #pragma unroll
            for (int rr = 0; rr < 4; ++rr)
                dz1v[nt][rr] = acc[nt][rr] * bf2f(s1s[e4[rr] * 128 + col]);
        }
    }
    __syncthreads();   // ts/w1s/vs/s1s reads all complete

    // ---- Phase B: write dz1s; stage w2s + s2s
    #pragma unroll
    for (int nt = 0; nt < 8; ++nt) {
        int col = nt * 16 + r16;
        #pragma unroll
        for (int rr = 0; rr < 4; ++rr)
            dz1s[(rbase + rr) * 136 + col] = f2bf(dz1v[nt][rr]);
    }
    #pragma unroll
    for (int q = 0; q < 8; ++q) {
        int idx = q * 256 + tid;
        int row = idx >> 4, u4 = idx & 15;
        cpu4(&w2s[row * 136 + u4 * 8], &wsb[W2B_OFF + row * 128 + u4 * 8]);
    }
    if (tid < 128) {
        int row = tid >> 4, u4 = tid & 15;
        cpu4(&s2s[row * 128 + u4 * 8], &S2g[(e0 + row) * 128 + u4 * 8]);
    }
    __syncthreads();

    // ---- jvp2: (dZ1 @ W2^T) .* s2[e] -> registers   M=64 N=128 K=128
    float dz2v[8][4];
    {
        const unsigned short* Ab = dz1s + (w * 16 + r16) * 136 + kb * 8;
        bf16x8 a[4];
        #pragma unroll
        for (int ks = 0; ks < 4; ++ks) a[ks] = ldfrag(Ab + ks * 32);
        f32x4 acc[8] = {};
        #pragma unroll
        for (int nt = 0; nt < 8; ++nt) {
            const unsigned short* Bb = w2s + (nt * 16 + r16) * 136 + kb * 8;
            #pragma unroll
            for (int ks = 0; ks < 4; ++ks)
                acc[nt] = __builtin_amdgcn_mfma_f32_16x16x32_bf16(a[ks], ldfrag(Bb + ks * 32), acc[nt], 0, 0, 0);
        }
        #pragma unroll
        for (int nt = 0; nt < 8; ++nt) {
            int col = nt * 16 + r16;
            #pragma unroll
            for (int rr = 0; rr < 4; ++rr)
                dz2v[nt][rr] = acc[nt][rr] * bf2f(s2s[e4[rr] * 128 + col]);
        }
    }
    __syncthreads();   // dz1s/w2s/s2s reads all complete

    // ---- Phase C: write dz2s; stage w3j0 + sig1f
    #pragma unroll
    for (int nt = 0; nt < 8; ++nt) {
        int col = nt * 16 + r16;
        #pragma unroll
        for (int rr = 0; rr < 4; ++rr)
            dz2s[(rbase + rr) * 136 + col] = f2bf(dz2v[nt][rr]);
    }
    #pragma unroll
    for (int q = 0; q < 4; ++q) {
        int idx = q * 256 + tid;
        int row = idx >> 4, u4 = idx & 15;
        cpu4(&w3j0[row * 136 + u4 * 8], &wsb[W3B_OFF + row * 128 + u4 * 8]);
    }
    if (tid < 64) {
        sig1f[tid] = sigg[(e0 + (tid >> 3)) * 36 + (tid & 7)];  // sig1f[e*8+j]
    }
    __syncthreads();

    // ---- jvp3 loop: wave w = n-tile w; per j, A rows j*8..j*8+7 (mt=j>>1, half=j&1)
    const int np = w * 16 + r16;
    const int myhalf = kb >> 1;            // crow>>3
    float oacc[4] = {};

    #pragma unroll
    for (int j = 0; j < 8; ++j) {
        unsigned short* cur = (j & 1) ? w3j1 : w3j0;
        unsigned short* nxt = (j & 1) ? w3j0 : w3j1;
        if (j < 7) {
            #pragma unroll
            for (int q = 0; q < 4; ++q) {
                int idx = q * 256 + tid;
                int row = idx >> 4, u4 = idx & 15;
                cpu4(&nxt[row * 136 + u4 * 8], &wsb[W3B_OFF + ((j + 1) * 64 + row) * 128 + u4 * 8]);
            }
        }
        int mt = j >> 1;
        const unsigned short* Ab = dz2s + (mt * 16 + r16) * 136 + kb * 8;
        bf16x8 a[4];
        #pragma unroll
        for (int ks = 0; ks < 4; ++ks) a[ks] = ldfrag(Ab + ks * 32);
        const unsigned short* Bb = cur + np * 136 + kb * 8;
        f32x4 acc = {};
        #pragma unroll
        for (int ks = 0; ks < 4; ++ks)
            acc = __builtin_amdgcn_mfma_f32_16x16x32_bf16(a[ks], ldfrag(Bb + ks * 32), acc, 0, 0, 0);

        if (myhalf == (j & 1)) {
            #pragma unroll
            for (int rr = 0; rr < 4; ++rr) {
                int e = (crow + rr) & 7;
                float v = bf2f(Vg[(e0 + e) * 512 + j * 64 + np]);
                float sv = sig1f[e * 8 + j];
                oacc[rr] += sv * v + (1.f - v * v) * acc[rr];
            }
        }
        __syncthreads();   // cur reads done before restage; nxt visible for j+1; last: sig1f reads done
    }

    // ---- combine parities via pjf (overwrites sig1f region — barrier above separates)
    if (kb < 2) {
        #pragma unroll
        for (int rr = 0; rr < 4; ++rr)
            pjf[(crow + rr) * 64 + np] = oacc[rr];
    }
    __syncthreads();
    if (kb >= 2) {
        #pragma unroll
        for (int rr = 0; rr < 4; ++rr) {
            int e = (crow - 8) + rr;
            out[(e0 + e) * 64 + np] = pjf[e * 64 + np] + oacc[rr];
        }
    }
}

extern "C" void kernel_launch(void* const* d_in, const int* in_sizes, int n_in,
                              void* d_out, int out_size, void* d_ws, size_t ws_size,
                              hipStream_t stream) {
    const float* hg  = (const float*)d_in[0];
    const float* sg  = (const float*)d_in[1];
    const float* W1  = (const float*)d_in[2];
    const float* b1  = (const float*)d_in[3];
    const float* W2  = (const float*)d_in[4];
    const float* b2  = (const float*)d_in[5];
    const float* W3  = (const float*)d_in[6];
    const float* b3  = (const float*)d_in[7];
    float* outp = (float*)d_out;
    unsigned short* wsb = (unsigned short*)d_ws;

    hipLaunchKernelGGL(prep_weights, dim3((WS_WEIGHTS + 255) / 256), dim3(256), 0, stream,
                       W1, W2, W3, wsb);
    hipLaunchKernelGGL(k12_fwd, dim3(NEL / 16), dim3(256), 0, stream, hg, b1, b2, b3, wsb);
    hipLaunchKernelGGL(k3_all, dim3(NEL / 8), dim3(256), 0, stream, sg, wsb, outp);
}

// Round 14
// 73.571 us; speedup vs baseline: 1.2640x; 1.1508x over previous
//
#include <hip/hip_runtime.h>
#include <hip/hip_bf16.h>

#define NEL 16384

// ---- workspace layout (offsets in SHORTS from d_ws base) ----
#define W1B_OFF 0                         // bf16 W1 [128][64]
#define W2B_OFF 8192                      // bf16 W2 [128][128]
#define W3B_OFF 24576                     // bf16 W3 [512][128]
#define WS_WEIGHTS 90112
#define S1_OFF  90112                     // bf16 [NEL][128]
#define S2_OFF  (S1_OFF + NEL*128)
#define V_OFF   (S2_OFF + NEL*128)        // bf16 [NEL][512]
#define DZ2_OFF (V_OFF + NEL*512)         // bf16 [NEL*8][128]  (row m = e*8+j)

typedef __attribute__((ext_vector_type(8))) short bf16x8;
typedef __attribute__((ext_vector_type(4))) float f32x4;

__device__ __forceinline__ float bf2f(unsigned int u16) {
    unsigned int x = u16 << 16;
    float f; __builtin_memcpy(&f, &x, 4); return f;
}
__device__ __forceinline__ unsigned short f2bf(float f) {
    unsigned int x; __builtin_memcpy(&x, &f, 4);
    x = (x + 0x7FFFu + ((x >> 16) & 1u)) >> 16;
    return (unsigned short)x;
}
__device__ __forceinline__ void unpack8(uint4 q, float* f) {
    f[0] = bf2f(q.x & 0xFFFFu); f[1] = bf2f(q.x >> 16);
    f[2] = bf2f(q.y & 0xFFFFu); f[3] = bf2f(q.y >> 16);
    f[4] = bf2f(q.z & 0xFFFFu); f[5] = bf2f(q.z >> 16);
    f[6] = bf2f(q.w & 0xFFFFu); f[7] = bf2f(q.w >> 16);
}
__device__ __forceinline__ void sp_sig(float x, float& sp, float& sig) {
    float t = __expf(-fabsf(x));
    float r = __builtin_amdgcn_rcpf(1.f + t);
    sig = (x >= 0.f) ? r : 1.f - r;
    sp  = fmaxf(x, 0.f) + __logf(1.f + t);
}
__device__ __forceinline__ float tanh_fast(float x) {
    float t = __expf(-2.f * fabsf(x));
    float y = (1.f - t) * __builtin_amdgcn_rcpf(1.f + t);
    unsigned int xb, yb;
    __builtin_memcpy(&xb, &x, 4);
    __builtin_memcpy(&yb, &y, 4);
    yb |= (xb & 0x80000000u);
    float rr; __builtin_memcpy(&rr, &yb, 4);
    return rr;
}
__device__ __forceinline__ bf16x8 ldfrag(const unsigned short* p) {
    return *reinterpret_cast<const bf16x8*>(p);
}
__device__ __forceinline__ void cpu4(unsigned short* dst, const unsigned short* src) {
    *reinterpret_cast<uint4*>(dst) = *reinterpret_cast<const uint4*>(src);
}

// ---- prep: bf16 copies of W1, W2, W3 in [out][k] layout ----
__global__ void prep_weights(const float* __restrict__ W1,
                             const float* __restrict__ W2,
                             const float* __restrict__ W3,
                             unsigned short* __restrict__ wb) {
    int i = blockIdx.x * blockDim.x + threadIdx.x;
    if (i >= WS_WEIGHTS) return;
    float v;
    if (i < W2B_OFF) v = W1[i];
    else if (i < W3B_OFF) v = W2[i - W2B_OFF];
    else v = W3[i - W3B_OFF];
    wb[i] = f2bf(v);
}

// ============ K12: fwd1 + fwd2 + fwd3 (R11 version — proven) ============
#define K12_LDS 39168
__global__ __launch_bounds__(256, 4)
void k12_fwd(const float* __restrict__ hg,
             const float* __restrict__ b1,
             const float* __restrict__ b2,
             const float* __restrict__ b3,
             unsigned short* __restrict__ wsb) {
    __shared__ __align__(16) char sm[K12_LDS];
    unsigned short* w1s = (unsigned short*)(sm);            // [128][72]
    unsigned short* hs  = (unsigned short*)(sm + 18432);    // [16][72]
    unsigned short* w2s = (unsigned short*)(sm);            // [128][136] phase2
    unsigned short* wc  = (unsigned short*)(sm);            // [128][136] phase3
    unsigned short* z1s = (unsigned short*)(sm + 34816);    // [16][136]
    unsigned short* z2s = (unsigned short*)(sm + 34816);    // [16][136] overlays z1s
    unsigned short* S1g = wsb + S1_OFF;
    unsigned short* S2g = wsb + S2_OFF;
    unsigned short* Vg  = wsb + V_OFF;

    const int tid = threadIdx.x;
    const int e0 = blockIdx.x * 16;
    const int lane = tid & 63;
    const int w = tid >> 6;
    const int r16 = lane & 15;
    const int kb = lane >> 4;
    const int crow = kb * 4;

    #pragma unroll
    for (int q = 0; q < 4; ++q) {
        int idx = q * 256 + tid;
        int row = idx >> 3, u4 = idx & 7;
        cpu4(&w1s[row * 72 + u4 * 8], &wsb[W1B_OFF + row * 64 + u4 * 8]);
    }
    {
        int row = tid >> 4, f4 = tid & 15;
        float4 hv = *reinterpret_cast<const float4*>(&hg[(e0 + row) * 64 + f4 * 4]);
        ushort2 lo = { f2bf(hv.x), f2bf(hv.y) };
        ushort2 hi = { f2bf(hv.z), f2bf(hv.w) };
        *reinterpret_cast<ushort2*>(&hs[row * 72 + f4 * 4]) = lo;
        *reinterpret_cast<ushort2*>(&hs[row * 72 + f4 * 4 + 2]) = hi;
    }
    __syncthreads();

    // fwd1: M=16 N=128 K=64
    {
        const unsigned short* Ab = hs + r16 * 72 + kb * 8;
        bf16x8 a0 = ldfrag(Ab), a1 = ldfrag(Ab + 32);
        f32x4 acc[2] = {};
        #pragma unroll
        for (int t = 0; t < 2; ++t) {
            int col16 = (w * 2 + t) * 16 + r16;
            const unsigned short* Bb = w1s + col16 * 72 + kb * 8;
            acc[t] = __builtin_amdgcn_mfma_f32_16x16x32_bf16(a0, ldfrag(Bb), acc[t], 0, 0, 0);
            acc[t] = __builtin_amdgcn_mfma_f32_16x16x32_bf16(a1, ldfrag(Bb + 32), acc[t], 0, 0, 0);
        }
        #pragma unroll
        for (int t = 0; t < 2; ++t) {
            int col = (w * 2 + t) * 16 + r16;
            float bb = b1[col];
            #pragma unroll
            for (int rr = 0; rr < 4; ++rr) {
                int e = crow + rr;
                float sp, sg;
                sp_sig(acc[t][rr] + bb, sp, sg);
                z1s[e * 136 + col] = f2bf(sp);
                S1g[(e0 + e) * 128 + col] = f2bf(sg);
            }
        }
    }
    __syncthreads();

    #pragma unroll
    for (int q = 0; q < 8; ++q) {
        int idx = q * 256 + tid;
        int row = idx >> 4, u4 = idx & 15;
        cpu4(&w2s[row * 136 + u4 * 8], &wsb[W2B_OFF + row * 128 + u4 * 8]);
    }
    __syncthreads();

    // fwd2: race-protected overlay (A-frags held in regs behind barrier)
    {
        const unsigned short* Ab = z1s + r16 * 136 + kb * 8;
        bf16x8 a[4];
        #pragma unroll
        for (int ks = 0; ks < 4; ++ks) a[ks] = ldfrag(Ab + ks * 32);
        __syncthreads();
        f32x4 acc[2] = {};
        #pragma unroll
        for (int t = 0; t < 2; ++t) {
            int col16 = (w * 2 + t) * 16 + r16;
            const unsigned short* Bb = w2s + col16 * 136 + kb * 8;
            #pragma unroll
            for (int ks = 0; ks < 4; ++ks)
                acc[t] = __builtin_amdgcn_mfma_f32_16x16x32_bf16(a[ks], ldfrag(Bb + ks * 32), acc[t], 0, 0, 0);
        }
        #pragma unroll
        for (int t = 0; t < 2; ++t) {
            int col = (w * 2 + t) * 16 + r16;
            float bb = b2[col];
            #pragma unroll
            for (int rr = 0; rr < 4; ++rr) {
                int e = crow + rr;
                float sp, sg;
                sp_sig(acc[t][rr] + bb, sp, sg);
                z2s[e * 136 + col] = f2bf(sp);
                S2g[(e0 + e) * 128 + col] = f2bf(sg);
            }
        }
    }

    // fwd3: 4 chunks of 128 cols; wc overlays w2s
    for (int nc = 0; nc < 4; ++nc) {
        __syncthreads();
        #pragma unroll
        for (int q = 0; q < 8; ++q) {
            int idx = q * 256 + tid;
            int row = idx >> 4, u4 = idx & 15;
            cpu4(&wc[row * 136 + u4 * 8], &wsb[W3B_OFF + (nc * 128 + row) * 128 + u4 * 8]);
        }
        __syncthreads();

        const unsigned short* Ab = z2s + r16 * 136 + kb * 8;
        bf16x8 a[4];
        #pragma unroll
        for (int ks = 0; ks < 4; ++ks) a[ks] = ldfrag(Ab + ks * 32);
        f32x4 acc[2] = {};
        #pragma unroll
        for (int t = 0; t < 2; ++t) {
            int col16 = (w * 2 + t) * 16 + r16;
            const unsigned short* Bb = wc + col16 * 136 + kb * 8;
            #pragma unroll
            for (int ks = 0; ks < 4; ++ks)
                acc[t] = __builtin_amdgcn_mfma_f32_16x16x32_bf16(a[ks], ldfrag(Bb + ks * 32), acc[t], 0, 0, 0);
        }
        #pragma unroll
        for (int t = 0; t < 2; ++t) {
            int c = nc * 128 + (w * 2 + t) * 16 + r16;
            float bb = b3[c];
            #pragma unroll
            for (int rr = 0; rr < 4; ++rr) {
                int e = crow + rr;
                float v = tanh_fast(acc[t][rr] + bb);
                Vg[(e0 + e) * 512 + c] = f2bf(v);
            }
        }
    }
}

// ============ K3: T-build + jvp1 + jvp2 — LDS diet: 35968 B -> 4 blocks/CU ============
// 8 elems/block, grid 2048 -> exactly 2 rounds at 4/CU.
// Phase A: w1s[128][72]@0 (18432) | ts[64][72]@18432 (9216) | sigs[288]f32@34816 (1152)
//          (V read DIRECTLY from global in T-build — no vs stage)
// Phase B: dz1s[64][136]@0 (17408) | w2sh[64][136]@17408 (17408) — W2 staged in halves
#define K3_LDS 35968
__global__ __launch_bounds__(256, 4)
void k3_jvp12(const float* __restrict__ sigg,
              unsigned short* __restrict__ wsb) {
    __shared__ __align__(16) char sm[K3_LDS];
    unsigned short* w1s  = (unsigned short*)(sm);           // [128][72]   phase A
    unsigned short* ts   = (unsigned short*)(sm + 18432);   // [64][72]    phase A
    float*          sigsm= (float*)(sm + 34816);            // [288]       phase A
    unsigned short* dz1s = (unsigned short*)(sm);           // [64][136]   phase B
    unsigned short* w2sh = (unsigned short*)(sm + 17408);   // [64][136]   phase B (half)
    const unsigned short* S1g = wsb + S1_OFF;
    const unsigned short* S2g = wsb + S2_OFF;
    const unsigned short* Vg  = wsb + V_OFF;
    unsigned short* DZ2g = wsb + DZ2_OFF;

    const int tid = threadIdx.x;
    const int e0 = blockIdx.x * 8;
    const int lane = tid & 63;
    const int w = tid >> 6;
    const int r16 = lane & 15;
    const int kb = lane >> 4;

    // ---- Phase A stage: W1 + sigs only
    #pragma unroll
    for (int q = 0; q < 4; ++q) {
        int idx = q * 256 + tid;
        int row = idx >> 3, u4 = idx & 7;
        cpu4(&w1s[row * 72 + u4 * 8], &wsb[W1B_OFF + row * 64 + u4 * 8]);
    }
    #pragma unroll
    for (int q = 0; q < 2; ++q) {
        int idx = q * 256 + tid;
        if (idx < 288) sigsm[idx] = sigg[e0 * 36 + idx];
    }
    __syncthreads();   // B1

    // ---- T-build: T[m=e*8+j][k] = sum_i c[i][j]_e * V[e][i*64+k]; V direct from global
    {
        int m = tid >> 2, kq = tid & 3;
        int e = m >> 3, j = m & 7;
        float c8[8];
        #pragma unroll
        for (int i = 0; i < 8; ++i) {
            float v = 0.f;
            if (i < j) {
                int p = 7 * i - i * (i - 1) / 2 + (j - i - 1);
                v = sigsm[e * 36 + 8 + p];
            } else if (i > j) {
                int p = 7 * j - j * (j - 1) / 2 + (i - j - 1);
                v = -sigsm[e * 36 + 8 + p];
            }
            c8[i] = v;
        }
        const unsigned short* Vrow = &Vg[(e0 + e) * 512 + kq * 16];
        float acc[16] = {};
        #pragma unroll
        for (int i = 0; i < 8; ++i) {
            uint4 qa = *reinterpret_cast<const uint4*>(Vrow + i * 64);
            uint4 qb = *reinterpret_cast<const uint4*>(Vrow + i * 64 + 8);
            float fa[8], fb[8];
            unpack8(qa, fa); unpack8(qb, fb);
            #pragma unroll
            for (int kk = 0; kk < 8; ++kk) {
                acc[kk]     += c8[i] * fa[kk];
                acc[kk + 8] += c8[i] * fb[kk];
            }
        }
        unsigned short o[16];
        #pragma unroll
        for (int kk = 0; kk < 16; ++kk) o[kk] = f2bf(acc[kk]);
        uint4 qo;
        qo.x = (unsigned int)o[0] | ((unsigned int)o[1] << 16);
        qo.y = (unsigned int)o[2] | ((unsigned int)o[3] << 16);
        qo.z = (unsigned int)o[4] | ((unsigned int)o[5] << 16);
        qo.w = (unsigned int)o[6] | ((unsigned int)o[7] << 16);
        *reinterpret_cast<uint4*>(&ts[m * 72 + kq * 16]) = qo;
        qo.x = (unsigned int)o[8]  | ((unsigned int)o[9]  << 16);
        qo.y = (unsigned int)o[10] | ((unsigned int)o[11] << 16);
        qo.z = (unsigned int)o[12] | ((unsigned int)o[13] << 16);
        qo.w = (unsigned int)o[14] | ((unsigned int)o[15] << 16);
        *reinterpret_cast<uint4*>(&ts[m * 72 + kq * 16 + 8]) = qo;
    }
    __syncthreads();   // B2

    // ---- jvp1: (T @ W1^T) .* s1[e] -> registers   M=64 N=128 K=64
    float dz1v[8][4];
    const int rbase = w * 16 + kb * 4;
    const int e_loc = rbase >> 3;               // rbase&7 in {0,4} -> constant over rr
    {
        const unsigned short* Ab = ts + (w * 16 + r16) * 72 + kb * 8;
        bf16x8 a0 = ldfrag(Ab), a1 = ldfrag(Ab + 32);
        f32x4 acc[8] = {};
        #pragma unroll
        for (int nt = 0; nt < 8; ++nt) {
            const unsigned short* Bb = w1s + (nt * 16 + r16) * 72 + kb * 8;
            acc[nt] = __builtin_amdgcn_mfma_f32_16x16x32_bf16(a0, ldfrag(Bb), acc[nt], 0, 0, 0);
            acc[nt] = __builtin_amdgcn_mfma_f32_16x16x32_bf16(a1, ldfrag(Bb + 32), acc[nt], 0, 0, 0);
        }
        #pragma unroll
        for (int nt = 0; nt < 8; ++nt) {
            int col = nt * 16 + r16;
            float s1v = bf2f(S1g[(e0 + e_loc) * 128 + col]);
            #pragma unroll
            for (int rr = 0; rr < 4; ++rr)
                dz1v[nt][rr] = acc[nt][rr] * s1v;
        }
    }
    __syncthreads();   // B3: ts/w1s reads complete before overlay writes

    // ---- Phase B: write dz1s (overlays w1s head); stage W2 half 0 (rows 0..63)
    #pragma unroll
    for (int nt = 0; nt < 8; ++nt) {
        int col = nt * 16 + r16;
        #pragma unroll
        for (int rr = 0; rr < 4; ++rr)
            dz1s[(rbase + rr) * 136 + col] = f2bf(dz1v[nt][rr]);
    }
    #pragma unroll
    for (int q = 0; q < 4; ++q) {
        int idx = q * 256 + tid;
        int row = idx >> 4, u4 = idx & 15;
        cpu4(&w2sh[row * 136 + u4 * 8], &wsb[W2B_OFF + row * 128 + u4 * 8]);
    }
    __syncthreads();   // B4

    // A-frags loaded ONCE, live across both halves
    bf16x8 a2[4];
    {
        const unsigned short* Ab = dz1s + (w * 16 + r16) * 136 + kb * 8;
        #pragma unroll
        for (int ks = 0; ks < 4; ++ks) a2[ks] = ldfrag(Ab + ks * 32);
    }

    // ---- jvp2 half 0: cols 0..63
    {
        f32x4 acc[4] = {};
        #pragma unroll
        for (int nt = 0; nt < 4; ++nt) {
            const unsigned short* Bb = w2sh + (nt * 16 + r16) * 136 + kb * 8;
            #pragma unroll
            for (int ks = 0; ks < 4; ++ks)
                acc[nt] = __builtin_amdgcn_mfma_f32_16x16x32_bf16(a2[ks], ldfrag(Bb + ks * 32), acc[nt], 0, 0, 0);
        }
        #pragma unroll
        for (int nt = 0; nt < 4; ++nt) {
            int col = nt * 16 + r16;
            float s2v = bf2f(S2g[(e0 + e_loc) * 128 + col]);
            #pragma unroll
            for (int rr = 0; rr < 4; ++rr)
                DZ2g[(e0 * 8 + rbase + rr) * 128 + col] = f2bf(acc[nt][rr] * s2v);
        }
    }
    __syncthreads();   // B5: half-0 reads complete

    // stage W2 half 1 (rows 64..127)
    #pragma unroll
    for (int q = 0; q < 4; ++q) {
        int idx = q * 256 + tid;
        int row = idx >> 4, u4 = idx & 15;
        cpu4(&w2sh[row * 136 + u4 * 8], &wsb[W2B_OFF + (64 + row) * 128 + u4 * 8]);
    }
    __syncthreads();   // B6

    // ---- jvp2 half 1: cols 64..127
    {
        f32x4 acc[4] = {};
        #pragma unroll
        for (int nt = 0; nt < 4; ++nt) {
            const unsigned short* Bb = w2sh + (nt * 16 + r16) * 136 + kb * 8;
            #pragma unroll
            for (int ks = 0; ks < 4; ++ks)
                acc[nt] = __builtin_amdgcn_mfma_f32_16x16x32_bf16(a2[ks], ldfrag(Bb + ks * 32), acc[nt], 0, 0, 0);
        }
        #pragma unroll
        for (int nt = 0; nt < 4; ++nt) {
            int col = 64 + nt * 16 + r16;
            float s2v = bf2f(S2g[(e0 + e_loc) * 128 + col]);
            #pragma unroll
            for (int rr = 0; rr < 4; ++rr)
                DZ2g[(e0 * 8 + rbase + rr) * 128 + col] = f2bf(acc[nt][rr] * s2v);
        }
    }
}

// ============ K4: jvp3 + mask + level-1 (R11 version — proven) ============
#define K4_LDS 35392
__global__ __launch_bounds__(256, 4)
void k4_jvp3(const float* __restrict__ sigg,
             const unsigned short* __restrict__ wsb,
             float* __restrict__ out) {
    __shared__ __align__(16) char sm[K4_LDS];
    unsigned short* w3j0 = (unsigned short*)(sm);            // [64][136]
    unsigned short* w3j1 = (unsigned short*)(sm + 17408);    // [64][136]
    float*          sg1  = (float*)(sm + 34816);             // [16][9]
    const unsigned short* Vg = wsb + V_OFF;
    const unsigned short* DZ2g = wsb + DZ2_OFF;

    const int tid = threadIdx.x;
    const int e0 = blockIdx.x * 16;
    const int lane = tid & 63;
    const int w = tid >> 6;
    const int r16 = lane & 15;
    const int kb = lane >> 4;
    const int crow = kb * 4;
    const int np = w * 16 + r16;

    if (tid < 128) {
        int e = tid >> 3, j7 = tid & 7;
        sg1[e * 9 + j7] = sigg[(e0 + e) * 36 + j7];
    }
    #pragma unroll
    for (int q = 0; q < 4; ++q) {
        int idx = q * 256 + tid;
        int row = idx >> 4, u4 = idx & 15;
        cpu4(&w3j0[row * 136 + u4 * 8], &wsb[W3B_OFF + row * 128 + u4 * 8]);
    }
    __syncthreads();

    float oacc[4] = {};
    const unsigned short* Agbase = DZ2g + (e0 + r16) * 8 * 128 + kb * 8;

    for (int j = 0; j < 8; ++j) {
        unsigned short* cur = (j & 1) ? w3j1 : w3j0;
        unsigned short* nxt = (j & 1) ? w3j0 : w3j1;
        if (j < 7) {
            #pragma unroll
            for (int q = 0; q < 4; ++q) {
                int idx = q * 256 + tid;
                int row = idx >> 4, u4 = idx & 15;
                cpu4(&nxt[row * 136 + u4 * 8], &wsb[W3B_OFF + ((j + 1) * 64 + row) * 128 + u4 * 8]);
            }
        }
        const unsigned short* Ag = Agbase + j * 128;
        bf16x8 a[4];
        #pragma unroll
        for (int ks = 0; ks < 4; ++ks) a[ks] = ldfrag(Ag + ks * 32);
        f32x4 acc = {};
        const unsigned short* Bb = cur + np * 136 + kb * 8;
        #pragma unroll
        for (int ks = 0; ks < 4; ++ks)
            acc = __builtin_amdgcn_mfma_f32_16x16x32_bf16(a[ks], ldfrag(Bb + ks * 32), acc, 0, 0, 0);

        #pragma unroll
        for (int rr = 0; rr < 4; ++rr) {
            int e = crow + rr;
            float v = bf2f(Vg[(e0 + e) * 512 + j * 64 + np]);
            float sv = sg1[e * 9 + j];
            oacc[rr] += sv * v + (1.f - v * v) * acc[rr];
        }
        __syncthreads();
    }

    #pragma unroll
    for (int rr = 0; rr < 4; ++rr)
        out[(e0 + crow + rr) * 64 + np] = oacc[rr];
}

extern "C" void kernel_launch(void* const* d_in, const int* in_sizes, int n_in,
                              void* d_out, int out_size, void* d_ws, size_t ws_size,
                              hipStream_t stream) {
    const float* hg  = (const float*)d_in[0];
    const float* sg  = (const float*)d_in[1];
    const float* W1  = (const float*)d_in[2];
    const float* b1  = (const float*)d_in[3];
    const float* W2  = (const float*)d_in[4];
    const float* b2  = (const float*)d_in[5];
    const float* W3  = (const float*)d_in[6];
    const float* b3  = (const float*)d_in[7];
    float* outp = (float*)d_out;
    unsigned short* wsb = (unsigned short*)d_ws;

    hipLaunchKernelGGL(prep_weights, dim3((WS_WEIGHTS + 255) / 256), dim3(256), 0, stream,
                       W1, W2, W3, wsb);
    hipLaunchKernelGGL(k12_fwd, dim3(NEL / 16), dim3(256), 0, stream, hg, b1, b2, b3, wsb);
    hipLaunchKernelGGL(k3_jvp12, dim3(NEL / 8), dim3(256), 0, stream, sg, wsb);
    hipLaunchKernelGGL(k4_jvp3, dim3(NEL / 16), dim3(256), 0, stream, sg, wsb, outp);
}